// Round 6
// baseline (60.072 us; speedup 1.0000x reference)
//
#include <hip/hip_runtime.h>

// BilinearSampler: image (B,H,W,C) f32, grid (B,H,W,2) f32 -> out (B,H,W,C) f32
// B=16, H=256, W=256, C=32.
//
// R5: L2-residency attack. Gather traffic (512MiB logical) was timed at
// ~L3-BW (36.7us ~= 512MiB/14TB/s). Force gathers to be L2-served:
//  - per-XCD single-batch schedule: XCD k does batch k (epoch 0), then
//    batch k+8 (epoch 1). Instantaneous image working set = 2.1MiB < 4MiB L2.
//  - NT grid loads + NT stores: keep the two streamed arrays out of L2.
//  - PX=4 pixels/thread (ILP saturated at this point, R3==R4).

constexpr int Bn = 16, Hn = 256, Wn = 256, Cn = 32;
constexpr int PX = 4;   // pixels per thread

typedef float f32x2 __attribute__((ext_vector_type(2)));
typedef float f32x4 __attribute__((ext_vector_type(4)));

__global__ __launch_bounds__(256) void BilinearSampler_29300266893747_kernel(
    const float* __restrict__ image,
    const float* __restrict__ grid,
    float* __restrict__ out)
{
    // 8192 blocks, 512 blocks per batch, XCD(bid) = bid % 8 (round-robin).
    // epoch 0 (bid < 4096): XCD k -> batch k.  epoch 1: XCD k -> batch k+8.
    const unsigned bid   = blockIdx.x;
    const unsigned epoch = bid >> 12;          // 0 or 1
    const unsigned r     = bid & 4095u;
    const unsigned wid   = (epoch << 12) + (r & 7u) * 512u + (r >> 3);

    const int tid = threadIdx.x;
    const int q   = tid & 7;        // channel quad: channels q*4..q*4+3
    const int s   = tid >> 3;       // pixel slot in [0,32)
    const int co  = q * 4;

    const long long base = (long long)wid * (32 * PX);  // 128 pixels per block
    const int b = (int)(base >> 16);   // 65536 % 128 == 0: no batch straddle
    const float* img_b = image + (long long)b * Hn * Wn * Cn;

    long long p[PX];
#pragma unroll
    for (int i = 0; i < PX; ++i) p[i] = base + 32 * i + s;

    // ---- grid coords (streamed once -> non-temporal) ----
    f32x2 g[PX];
#pragma unroll
    for (int i = 0; i < PX; ++i)
        g[i] = __builtin_nontemporal_load((const f32x2*)grid + p[i]);

    // ---- compute offsets + weights ----
    int oa[PX], ob[PX], oc[PX], od[PX];
    float wa[PX], wb[PX], wc[PX], wd[PX];
#pragma unroll
    for (int i = 0; i < PX; ++i) {
        const float x = (g[i].x + 1.0f) * 255.0f * 0.5f;
        const float y = (g[i].y + 1.0f) * 255.0f * 0.5f;
        const float xf = floorf(x), yf = floorf(y);
        const int x0 = (int)xf, y0 = (int)yf;

        const int x0c = min(max(x0,     0), Wn - 1);
        const int x1c = min(max(x0 + 1, 0), Wn - 1);
        const int y0c = min(max(y0,     0), Hn - 1);
        const int y1c = min(max(y0 + 1, 0), Hn - 1);

        // element offsets within batch: (y*256 + x)*32 + co
        oa[i] = (y0c << 13) + (x0c << 5) + co;
        oc[i] = (y0c << 13) + (x1c << 5) + co;
        ob[i] = (y1c << 13) + (x0c << 5) + co;
        od[i] = (y1c << 13) + (x1c << 5) + co;

        const float x0f = (float)x0c, x1f = (float)x1c;
        const float y0f = (float)y0c, y1f = (float)y1c;
        wa[i] = (x1f - x) * (y1f - y);
        wb[i] = (x1f - x) * (y - y0f);
        wc[i] = (x - x0f) * (y1f - y);
        wd[i] = (x - x0f) * (y - y0f);
    }

    // ---- issue all 16 gathers before any use (regular loads -> L2-cached) ----
    f32x4 Ia[PX], Ib[PX], Ic[PX], Id[PX];
#pragma unroll
    for (int i = 0; i < PX; ++i) {
        Ia[i] = *(const f32x4*)(img_b + oa[i]);
        Ib[i] = *(const f32x4*)(img_b + ob[i]);
        Ic[i] = *(const f32x4*)(img_b + oc[i]);
        Id[i] = *(const f32x4*)(img_b + od[i]);
    }

    // ---- blend + NT store ----
#pragma unroll
    for (int i = 0; i < PX; ++i) {
        const f32x4 o = wa[i] * Ia[i] + wb[i] * Ib[i] + wc[i] * Ic[i] + wd[i] * Id[i];
        __builtin_nontemporal_store(o, (f32x4*)(out + p[i] * Cn + co));
    }
}

extern "C" void kernel_launch(void* const* d_in, const int* in_sizes, int n_in,
                              void* d_out, int out_size, void* d_ws, size_t ws_size,
                              hipStream_t stream) {
    const float* image = (const float*)d_in[0];
    const float* grid  = (const float*)d_in[1];
    float* out = (float*)d_out;

    const long long total = (long long)Bn * Hn * Wn * 8 / PX;  // 2,097,152 threads
    const int block = 256;
    const int nblocks = (int)((total + block - 1) / block);    // 8192

    BilinearSampler_29300266893747_kernel<<<nblocks, block, 0, stream>>>(image, grid, out);
}

// Round 7
// 35.461 us; speedup vs baseline: 1.6940x; 1.6940x over previous
//
#include <hip/hip_runtime.h>

// BilinearSampler: image (B,H,W,C) f32, grid (B,H,W,2) f32 -> out (B,H,W,C) f32
// B=16, H=256, W=256, C=32.
//
// R6: exact R4 kernel (PX=4, temporal grid loads, NT stores) + ONLY the
// per-XCD single-batch schedule from R5 (epoch 0: XCD k -> batch k; epoch 1:
// XCD k -> batch k+8). Isolates schedule-concentration from the NT-grid-load
// variable that was confounded in R5.

constexpr int Bn = 16, Hn = 256, Wn = 256, Cn = 32;
constexpr int PX = 4;   // pixels per thread

typedef float f32x2 __attribute__((ext_vector_type(2)));
typedef float f32x4 __attribute__((ext_vector_type(4)));

__global__ __launch_bounds__(256) void BilinearSampler_29300266893747_kernel(
    const float* __restrict__ image,
    const float* __restrict__ grid,
    float* __restrict__ out)
{
    // 8192 blocks, 512 blocks per batch, XCD(bid) = bid % 8 (round-robin).
    // epoch 0 (bid < 4096): XCD k -> batch k.  epoch 1: XCD k -> batch k+8.
    const unsigned bid   = blockIdx.x;
    const unsigned epoch = bid >> 12;          // 0 or 1
    const unsigned r     = bid & 4095u;
    const unsigned wid   = (epoch << 12) + (r & 7u) * 512u + (r >> 3);

    const int tid = threadIdx.x;
    const int q   = tid & 7;        // channel quad: channels q*4..q*4+3
    const int s   = tid >> 3;       // pixel slot in [0,32)
    const int co  = q * 4;

    const long long base = (long long)wid * (32 * PX);  // 128 pixels per block
    const int b = (int)(base >> 16);   // 65536 % 128 == 0: no batch straddle
    const float* img_b = image + (long long)b * Hn * Wn * Cn;

    long long p[PX];
#pragma unroll
    for (int i = 0; i < PX; ++i) p[i] = base + 32 * i + s;

    // ---- grid coords: TEMPORAL loads (NT here regressed R5) ----
    f32x2 g[PX];
#pragma unroll
    for (int i = 0; i < PX; ++i) g[i] = *((const f32x2*)grid + p[i]);

    // ---- compute offsets + weights ----
    int oa[PX], ob[PX], oc[PX], od[PX];
    float wa[PX], wb[PX], wc[PX], wd[PX];
#pragma unroll
    for (int i = 0; i < PX; ++i) {
        const float x = (g[i].x + 1.0f) * 255.0f * 0.5f;
        const float y = (g[i].y + 1.0f) * 255.0f * 0.5f;
        const float xf = floorf(x), yf = floorf(y);
        const int x0 = (int)xf, y0 = (int)yf;

        const int x0c = min(max(x0,     0), Wn - 1);
        const int x1c = min(max(x0 + 1, 0), Wn - 1);
        const int y0c = min(max(y0,     0), Hn - 1);
        const int y1c = min(max(y0 + 1, 0), Hn - 1);

        // element offsets within batch: (y*256 + x)*32 + co
        oa[i] = (y0c << 13) + (x0c << 5) + co;
        oc[i] = (y0c << 13) + (x1c << 5) + co;
        ob[i] = (y1c << 13) + (x0c << 5) + co;
        od[i] = (y1c << 13) + (x1c << 5) + co;

        const float x0f = (float)x0c, x1f = (float)x1c;
        const float y0f = (float)y0c, y1f = (float)y1c;
        wa[i] = (x1f - x) * (y1f - y);
        wb[i] = (x1f - x) * (y - y0f);
        wc[i] = (x - x0f) * (y1f - y);
        wd[i] = (x - x0f) * (y - y0f);
    }

    // ---- issue all 16 gathers before any use ----
    f32x4 Ia[PX], Ib[PX], Ic[PX], Id[PX];
#pragma unroll
    for (int i = 0; i < PX; ++i) {
        Ia[i] = *(const f32x4*)(img_b + oa[i]);
        Ib[i] = *(const f32x4*)(img_b + ob[i]);
        Ic[i] = *(const f32x4*)(img_b + oc[i]);
        Id[i] = *(const f32x4*)(img_b + od[i]);
    }

    // ---- blend + NT store ----
#pragma unroll
    for (int i = 0; i < PX; ++i) {
        const f32x4 o = wa[i] * Ia[i] + wb[i] * Ib[i] + wc[i] * Ic[i] + wd[i] * Id[i];
        __builtin_nontemporal_store(o, (f32x4*)(out + p[i] * Cn + co));
    }
}

extern "C" void kernel_launch(void* const* d_in, const int* in_sizes, int n_in,
                              void* d_out, int out_size, void* d_ws, size_t ws_size,
                              hipStream_t stream) {
    const float* image = (const float*)d_in[0];
    const float* grid  = (const float*)d_in[1];
    float* out = (float*)d_out;

    const long long total = (long long)Bn * Hn * Wn * 8 / PX;  // 2,097,152 threads
    const int block = 256;
    const int nblocks = (int)((total + block - 1) / block);    // 8192

    BilinearSampler_29300266893747_kernel<<<nblocks, block, 0, stream>>>(image, grid, out);
}